// Round 1
// baseline (880.861 us; speedup 1.0000x reference)
//
#include <hip/hip_runtime.h>

// Layout facts (verified against the reference's reshapes):
//   x flat  = [CH=128][HW=262144]   (the B*4/C4 split preserves flat order)
//   out flat= [CH=128][S=32768]
// Per vote v: out[ch][s_v] += x[ch][ht_v] * w_v  for all ch in [0,128).
//
// Strategy: transpose x -> xT[HW][128] so each vote's 128-channel read is one
// contiguous 512B segment; accumulate into outT[S][128] (contiguous 512B of
// atomics per vote, 8 cache lines instead of 128); transpose back at the end.

__global__ void transpose_x_kernel(const float* __restrict__ x,
                                   float* __restrict__ xT, int HW) {
    // tile: 64 ht x 128 ch
    __shared__ float tile[64][129];   // +1 pad: stride 129 -> conflict-free
    const int ht0 = blockIdx.x * 64;
    const int tid = threadIdx.x;      // 256 threads
    // read phase: lanes sweep ht (coalesced on x rows)
    for (int e = tid; e < 128 * 64; e += 256) {
        const int ch = e >> 6;        // 0..127
        const int hl = e & 63;        // 0..63
        tile[hl][ch] = x[(size_t)ch * HW + ht0 + hl];
    }
    __syncthreads();
    // write phase: lanes sweep ch (coalesced on xT rows)
    for (int e = tid; e < 128 * 64; e += 256) {
        const int hl = e >> 7;        // 0..63
        const int ch = e & 127;       // 0..127
        xT[(size_t)(ht0 + hl) * 128 + ch] = tile[hl][ch];
    }
}

__global__ void votes_kernel(const float* __restrict__ xT,
                             const int* __restrict__ ht_idx,
                             const int* __restrict__ sp_idx,
                             const float* __restrict__ weight,
                             float* __restrict__ outT, int V) {
    // 256 threads = 2 votes per block, 128 channels each
    const int v = blockIdx.x * 2 + (threadIdx.x >> 7);
    if (v >= V) return;
    const int ch = threadIdx.x & 127;
    const int ht = ht_idx[v];
    const int s  = sp_idx[v];
    const float w = weight[v];
    const float val = xT[(size_t)ht * 128 + ch] * w;
    atomicAdd(&outT[(size_t)s * 128 + ch], val);
}

__global__ void transpose_out_kernel(const float* __restrict__ outT,
                                     float* __restrict__ out, int S) {
    // tile: 64 s x 128 ch
    __shared__ float tile[64][129];
    const int s0 = blockIdx.x * 64;
    const int tid = threadIdx.x;
    // read phase: lanes sweep ch (coalesced on outT rows)
    for (int e = tid; e < 128 * 64; e += 256) {
        const int sl = e >> 7;
        const int ch = e & 127;
        tile[sl][ch] = outT[(size_t)(s0 + sl) * 128 + ch];
    }
    __syncthreads();
    // write phase: lanes sweep s (coalesced on out rows)
    for (int e = tid; e < 128 * 64; e += 256) {
        const int ch = e >> 6;
        const int sl = e & 63;
        out[(size_t)ch * S + s0 + sl] = tile[sl][ch];
    }
}

// Fallback if workspace is too small: direct uncoalesced atomic version.
__global__ void direct_kernel(const float* __restrict__ x,
                              const int* __restrict__ ht_idx,
                              const int* __restrict__ sp_idx,
                              const float* __restrict__ weight,
                              float* __restrict__ out, int V, int HW, int S,
                              int CH) {
    const int v = blockIdx.x * 2 + (threadIdx.x >> 7);
    if (v >= V) return;
    const int ch = threadIdx.x & 127;
    if (ch >= CH) return;
    const int ht = ht_idx[v];
    const int s  = sp_idx[v];
    const float w = weight[v];
    atomicAdd(&out[(size_t)ch * S + s], x[(size_t)ch * HW + ht] * w);
}

extern "C" void kernel_launch(void* const* d_in, const int* in_sizes, int n_in,
                              void* d_out, int out_size, void* d_ws, size_t ws_size,
                              hipStream_t stream) {
    const float* x  = (const float*)d_in[0];
    const int*   ht = (const int*)d_in[1];
    const int*   sp = (const int*)d_in[2];
    const float* w  = (const float*)d_in[3];
    float* out = (float*)d_out;

    const int HW = 512 * 512;                 // HT grid, fixed by the module
    const int CH = in_sizes[0] / HW;          // = B*C = 128
    const int S  = out_size / CH;             // = 32768
    const int V  = in_sizes[1];               // = 1,500,000

    const size_t xT_bytes   = (size_t)CH * HW * sizeof(float);
    const size_t outT_bytes = (size_t)CH * S * sizeof(float);

    if (CH == 128 && ws_size >= xT_bytes + outT_bytes) {
        float* xT   = (float*)d_ws;
        float* outT = (float*)((char*)d_ws + xT_bytes);
        hipMemsetAsync(outT, 0, outT_bytes, stream);
        transpose_x_kernel<<<HW / 64, 256, 0, stream>>>(x, xT, HW);
        votes_kernel<<<(V + 1) / 2, 256, 0, stream>>>(xT, ht, sp, w, outT, V);
        transpose_out_kernel<<<S / 64, 256, 0, stream>>>(outT, out, S);
    } else {
        hipMemsetAsync(out, 0, (size_t)out_size * sizeof(float), stream);
        direct_kernel<<<(V + 1) / 2, 256, 0, stream>>>(x, ht, sp, w, out, V, HW, S, CH);
    }
}

// Round 2
// 601.264 us; speedup vs baseline: 1.4650x; 1.4650x over previous
//
#include <hip/hip_runtime.h>

// out[ch][s] = sum_{v: sp[v]==s} x[ch][ht[v]] * w[v],  ch in [0,128)
//
// R1 showed the atomic scatter writes 768 MB (V*512B) to the fabric — the
// bottleneck. R2: counting-sort votes by sphere bin, then one block per bin
// accumulates in registers and writes its 512B exactly once. No accumulator
// atomics.

#define S_BINS 32768

__global__ void transpose_x_kernel(const float* __restrict__ x,
                                   float* __restrict__ xT, int HW) {
    __shared__ float tile[64][129];
    const int ht0 = blockIdx.x * 64;
    const int tid = threadIdx.x;      // 256
    for (int e = tid; e < 128 * 64; e += 256) {
        const int ch = e >> 6, hl = e & 63;
        tile[hl][ch] = x[(size_t)ch * HW + ht0 + hl];
    }
    __syncthreads();
    for (int e = tid; e < 128 * 64; e += 256) {
        const int hl = e >> 7, ch = e & 127;
        xT[(size_t)(ht0 + hl) * 128 + ch] = tile[hl][ch];
    }
}

__global__ void hist_kernel(const int* __restrict__ sp, int* __restrict__ hist,
                            int V) {
    const int v = blockIdx.x * blockDim.x + threadIdx.x;
    if (v < V) atomicAdd(&hist[sp[v]], 1);
}

// Single block, 1024 threads, 32 bins/thread. In-place: hist -> exclusive offsets.
__global__ void scan_kernel(int* __restrict__ offsets, int* __restrict__ cursor) {
    __shared__ int lsum[1024];
    const int t = threadIdx.x;
    int vals[32];
    int sum = 0;
#pragma unroll
    for (int i = 0; i < 32; ++i) { vals[i] = offsets[t * 32 + i]; sum += vals[i]; }
    lsum[t] = sum;
    __syncthreads();
    for (int off = 1; off < 1024; off <<= 1) {
        const int add = (t >= off) ? lsum[t - off] : 0;
        __syncthreads();
        lsum[t] += add;
        __syncthreads();
    }
    int running = (t == 0) ? 0 : lsum[t - 1];
#pragma unroll
    for (int i = 0; i < 32; ++i) {
        offsets[t * 32 + i] = running;
        cursor[t * 32 + i]  = running;
        running += vals[i];
    }
    if (t == 1023) offsets[S_BINS] = running;  // == V
}

__global__ void scatter_kernel(const int* __restrict__ ht,
                               const int* __restrict__ sp,
                               const float* __restrict__ w,
                               int* __restrict__ cursor,
                               uint2* __restrict__ records, int V) {
    const int v = blockIdx.x * blockDim.x + threadIdx.x;
    if (v >= V) return;
    const int s = sp[v];
    const int pos = atomicAdd(&cursor[s], 1);
    records[pos] = make_uint2((unsigned)ht[v], __float_as_uint(w[v]));
}

// One block (256 thr = 2 vote-groups x 128 channels) per sphere bin.
__global__ void accum_kernel(const float* __restrict__ xT,
                             const uint2* __restrict__ records,
                             const int* __restrict__ offsets,
                             float* __restrict__ outT) {
    __shared__ uint2 rec[256];
    __shared__ float part[128];
    const int s   = blockIdx.x;
    const int tid = threadIdx.x;
    const int ch  = tid & 127;
    const int sub = tid >> 7;          // which vote-group
    const int start = offsets[s];
    const int end   = offsets[s + 1];
    float acc = 0.f;
    for (int base = start; base < end; base += 256) {
        const int chunk = min(256, end - base);
        __syncthreads();
        if (tid < chunk) rec[tid] = records[base + tid];
        __syncthreads();
        for (int k = sub; k < chunk; k += 2) {
            const uint2 r = rec[k];
            acc += xT[(size_t)r.x * 128 + ch] * __uint_as_float(r.y);
        }
    }
    if (sub == 1) part[ch] = acc;
    __syncthreads();
    if (sub == 0) outT[(size_t)s * 128 + ch] = acc + part[ch];
}

__global__ void transpose_out_kernel(const float* __restrict__ outT,
                                     float* __restrict__ out, int S) {
    __shared__ float tile[64][129];
    const int s0 = blockIdx.x * 64;
    const int tid = threadIdx.x;
    for (int e = tid; e < 128 * 64; e += 256) {
        const int sl = e >> 7, ch = e & 127;
        tile[sl][ch] = outT[(size_t)(s0 + sl) * 128 + ch];
    }
    __syncthreads();
    for (int e = tid; e < 128 * 64; e += 256) {
        const int ch = e >> 6, sl = e & 63;
        out[(size_t)ch * S + s0 + sl] = tile[sl][ch];
    }
}

// ---- fallbacks (R1 paths) ----
__global__ void votes_kernel(const float* __restrict__ xT,
                             const int* __restrict__ ht_idx,
                             const int* __restrict__ sp_idx,
                             const float* __restrict__ weight,
                             float* __restrict__ outT, int V) {
    const int v = blockIdx.x * 2 + (threadIdx.x >> 7);
    if (v >= V) return;
    const int ch = threadIdx.x & 127;
    atomicAdd(&outT[(size_t)sp_idx[v] * 128 + ch],
              xT[(size_t)ht_idx[v] * 128 + ch] * weight[v]);
}

__global__ void direct_kernel(const float* __restrict__ x,
                              const int* __restrict__ ht_idx,
                              const int* __restrict__ sp_idx,
                              const float* __restrict__ weight,
                              float* __restrict__ out, int V, int HW, int S,
                              int CH) {
    const int v = blockIdx.x * 2 + (threadIdx.x >> 7);
    if (v >= V) return;
    const int ch = threadIdx.x & 127;
    if (ch >= CH) return;
    atomicAdd(&out[(size_t)ch * S + sp_idx[v]],
              x[(size_t)ch * HW + ht_idx[v]] * weight[v]);
}

extern "C" void kernel_launch(void* const* d_in, const int* in_sizes, int n_in,
                              void* d_out, int out_size, void* d_ws, size_t ws_size,
                              hipStream_t stream) {
    const float* x  = (const float*)d_in[0];
    const int*   ht = (const int*)d_in[1];
    const int*   sp = (const int*)d_in[2];
    const float* w  = (const float*)d_in[3];
    float* out = (float*)d_out;

    const int HW = 512 * 512;
    const int CH = in_sizes[0] / HW;          // 128
    const int S  = out_size / CH;             // 32768
    const int V  = in_sizes[1];               // 1.5M

    const size_t xT_bytes   = (size_t)CH * HW * sizeof(float);
    const size_t outT_bytes = (size_t)CH * S * sizeof(float);
    const size_t rec_bytes  = (size_t)V * sizeof(uint2);
    const size_t off_bytes  = (size_t)(S + 1) * sizeof(int);
    // cursor aliases outT (outT written only after scatter completes)

    const size_t need_binned = xT_bytes + rec_bytes + off_bytes + outT_bytes;

    if (CH == 128 && S == S_BINS && ws_size >= need_binned) {
        char* p = (char*)d_ws;
        float* xT      = (float*)p;            p += xT_bytes;
        uint2* records = (uint2*)p;            p += rec_bytes;
        int*   offsets = (int*)p;              p += off_bytes;
        float* outT    = (float*)p;
        int*   cursor  = (int*)outT;           // alias

        hipMemsetAsync(offsets, 0, off_bytes, stream);
        transpose_x_kernel<<<HW / 64, 256, 0, stream>>>(x, xT, HW);
        hist_kernel<<<(V + 255) / 256, 256, 0, stream>>>(sp, offsets, V);
        scan_kernel<<<1, 1024, 0, stream>>>(offsets, cursor);
        scatter_kernel<<<(V + 255) / 256, 256, 0, stream>>>(ht, sp, w, cursor,
                                                            records, V);
        accum_kernel<<<S, 256, 0, stream>>>(xT, records, offsets, outT);
        transpose_out_kernel<<<S / 64, 256, 0, stream>>>(outT, out, S);
    } else if (CH == 128 && ws_size >= xT_bytes + outT_bytes) {
        float* xT   = (float*)d_ws;
        float* outT = (float*)((char*)d_ws + xT_bytes);
        hipMemsetAsync(outT, 0, outT_bytes, stream);
        transpose_x_kernel<<<HW / 64, 256, 0, stream>>>(x, xT, HW);
        votes_kernel<<<(V + 1) / 2, 256, 0, stream>>>(xT, ht, sp, w, outT, V);
        transpose_out_kernel<<<S / 64, 256, 0, stream>>>(outT, out, S);
    } else {
        hipMemsetAsync(out, 0, (size_t)out_size * sizeof(float), stream);
        direct_kernel<<<(V + 1) / 2, 256, 0, stream>>>(x, ht, sp, w, out, V, HW,
                                                       S, CH);
    }
}

// Round 3
// 516.040 us; speedup vs baseline: 1.7070x; 1.1651x over previous
//
#include <hip/hip_runtime.h>
#include <stdint.h>

// out[ch][s] = sum_{v: sp[v]==s} x[ch][ht[v]] * w[v],  ch in [0,128)
//
// R1: atomic scatter wrote 768 MB -> binned by sphere (R2, 601us).
// R2: accum gather of f32 xT is the bottleneck (373 MB FETCH, 180us).
// R3: xT stored as bf16 (packed bf16x2) -> half the gather bytes/lines.
//     accum: 64 lanes x bf16x2 = 256B coalesced per vote, f32 accumulate.

#define S_BINS 32768

__device__ __forceinline__ unsigned bf16_rne(float f) {
    unsigned u = __float_as_uint(f);
    return (u + 0x7FFFu + ((u >> 16) & 1u)) >> 16;   // round-nearest-even
}

// x [128][HW] f32  ->  xTb [HW][64] u32 (bf16x2: lo=ch even, hi=ch odd)
__global__ void transpose_x_bf16_kernel(const float* __restrict__ x,
                                        uint32_t* __restrict__ xTb, int HW) {
    __shared__ float tile[64][129];
    const int ht0 = blockIdx.x * 64;
    const int tid = threadIdx.x;      // 256
    for (int e = tid; e < 128 * 64; e += 256) {
        const int ch = e >> 6, hl = e & 63;
        tile[hl][ch] = x[(size_t)ch * HW + ht0 + hl];
    }
    __syncthreads();
    for (int e = tid; e < 64 * 64; e += 256) {
        const int hl = e >> 6, cp = e & 63;      // cp = channel pair
        const unsigned lo = bf16_rne(tile[hl][2 * cp]);
        const unsigned hi = bf16_rne(tile[hl][2 * cp + 1]);
        xTb[(size_t)(ht0 + hl) * 64 + cp] = lo | (hi << 16);
    }
}

__global__ void hist_kernel(const int* __restrict__ sp, int* __restrict__ hist,
                            int V) {
    const int v = blockIdx.x * blockDim.x + threadIdx.x;
    if (v < V) atomicAdd(&hist[sp[v]], 1);
}

// Single block, 1024 threads, 32 bins/thread. In-place: hist -> exclusive offsets.
__global__ void scan_kernel(int* __restrict__ offsets, int* __restrict__ cursor) {
    __shared__ int lsum[1024];
    const int t = threadIdx.x;
    int vals[32];
    int sum = 0;
#pragma unroll
    for (int i = 0; i < 32; ++i) { vals[i] = offsets[t * 32 + i]; sum += vals[i]; }
    lsum[t] = sum;
    __syncthreads();
    for (int off = 1; off < 1024; off <<= 1) {
        const int add = (t >= off) ? lsum[t - off] : 0;
        __syncthreads();
        lsum[t] += add;
        __syncthreads();
    }
    int running = (t == 0) ? 0 : lsum[t - 1];
#pragma unroll
    for (int i = 0; i < 32; ++i) {
        offsets[t * 32 + i] = running;
        cursor[t * 32 + i]  = running;
        running += vals[i];
    }
    if (t == 1023) offsets[S_BINS] = running;  // == V
}

__global__ void scatter_kernel(const int* __restrict__ ht,
                               const int* __restrict__ sp,
                               const float* __restrict__ w,
                               int* __restrict__ cursor,
                               uint2* __restrict__ records, int V) {
    const int v = blockIdx.x * blockDim.x + threadIdx.x;
    if (v >= V) return;
    const int s = sp[v];
    const int pos = atomicAdd(&cursor[s], 1);
    records[pos] = make_uint2((unsigned)ht[v], __float_as_uint(w[v]));
}

// One block per sphere bin. 256 thr = 4 vote-subgroups x 64 lanes.
// Lane handles channels {2*lane, 2*lane+1} via one bf16x2 word per vote.
__global__ void accum_bf16_kernel(const uint32_t* __restrict__ xTb,
                                  const uint2* __restrict__ records,
                                  const int* __restrict__ offsets,
                                  float2* __restrict__ outT2) {
    __shared__ uint2 rec[256];
    __shared__ float2 part[4][64];
    const int s    = blockIdx.x;
    const int tid  = threadIdx.x;
    const int lane = tid & 63;
    const int sub  = tid >> 6;         // 0..3
    const int start = offsets[s];
    const int end   = offsets[s + 1];
    float a0 = 0.f, a1 = 0.f;
    for (int base = start; base < end; base += 256) {
        const int chunk = min(256, end - base);
        __syncthreads();
        if (tid < chunk) rec[tid] = records[base + tid];
        __syncthreads();
        for (int k = sub; k < chunk; k += 4) {
            const uint2 r = rec[k];
            const uint32_t u = xTb[(size_t)r.x * 64 + lane];
            const float w = __uint_as_float(r.y);
            a0 += __uint_as_float(u << 16) * w;            // even channel
            a1 += __uint_as_float(u & 0xFFFF0000u) * w;    // odd channel
        }
    }
    part[sub][lane] = make_float2(a0, a1);
    __syncthreads();
    if (sub == 0) {
        const float2 p1 = part[1][lane], p2 = part[2][lane], p3 = part[3][lane];
        outT2[(size_t)s * 64 + lane] =
            make_float2(a0 + p1.x + p2.x + p3.x, a1 + p1.y + p2.y + p3.y);
    }
}

// outT [S][128] f32 -> out [128][S]
__global__ void transpose_out_kernel(const float* __restrict__ outT,
                                     float* __restrict__ out, int S) {
    __shared__ float tile[64][129];
    const int s0 = blockIdx.x * 64;
    const int tid = threadIdx.x;
    for (int e = tid; e < 128 * 64; e += 256) {
        const int sl = e >> 7, ch = e & 127;
        tile[sl][ch] = outT[(size_t)(s0 + sl) * 128 + ch];
    }
    __syncthreads();
    for (int e = tid; e < 128 * 64; e += 256) {
        const int ch = e >> 6, sl = e & 63;
        out[(size_t)ch * S + s0 + sl] = tile[sl][ch];
    }
}

// ---- fallback (direct atomic, any shape) ----
__global__ void direct_kernel(const float* __restrict__ x,
                              const int* __restrict__ ht_idx,
                              const int* __restrict__ sp_idx,
                              const float* __restrict__ weight,
                              float* __restrict__ out, int V, int HW, int S,
                              int CH) {
    const int v = blockIdx.x * 2 + (threadIdx.x >> 7);
    if (v >= V) return;
    const int ch = threadIdx.x & 127;
    if (ch >= CH) return;
    atomicAdd(&out[(size_t)ch * S + sp_idx[v]],
              x[(size_t)ch * HW + ht_idx[v]] * weight[v]);
}

extern "C" void kernel_launch(void* const* d_in, const int* in_sizes, int n_in,
                              void* d_out, int out_size, void* d_ws, size_t ws_size,
                              hipStream_t stream) {
    const float* x  = (const float*)d_in[0];
    const int*   ht = (const int*)d_in[1];
    const int*   sp = (const int*)d_in[2];
    const float* w  = (const float*)d_in[3];
    float* out = (float*)d_out;

    const int HW = 512 * 512;
    const int CH = in_sizes[0] / HW;          // 128
    const int S  = out_size / CH;             // 32768
    const int V  = in_sizes[1];               // 1.5M

    const size_t xTb_bytes  = (size_t)CH * HW * sizeof(uint16_t);   // 64 MB
    const size_t rec_bytes  = (size_t)V * sizeof(uint2);            // 12 MB
    const size_t off_bytes  = (size_t)(S + 1) * sizeof(int);
    const size_t outT_bytes = (size_t)CH * S * sizeof(float);       // 16 MB

    const size_t need = xTb_bytes + rec_bytes + off_bytes + outT_bytes;

    if (CH == 128 && S == S_BINS && ws_size >= need) {
        char* p = (char*)d_ws;
        uint32_t* xTb  = (uint32_t*)p;         p += xTb_bytes;
        uint2* records = (uint2*)p;            p += rec_bytes;
        int*   offsets = (int*)p;              p += off_bytes;
        float* outT    = (float*)p;
        int*   cursor  = (int*)outT;           // alias; outT written after scatter

        hipMemsetAsync(offsets, 0, off_bytes, stream);
        transpose_x_bf16_kernel<<<HW / 64, 256, 0, stream>>>(x, xTb, HW);
        hist_kernel<<<(V + 255) / 256, 256, 0, stream>>>(sp, offsets, V);
        scan_kernel<<<1, 1024, 0, stream>>>(offsets, cursor);
        scatter_kernel<<<(V + 255) / 256, 256, 0, stream>>>(ht, sp, w, cursor,
                                                            records, V);
        accum_bf16_kernel<<<S, 256, 0, stream>>>(xTb, records, offsets,
                                                 (float2*)outT);
        transpose_out_kernel<<<S / 64, 256, 0, stream>>>(outT, out, S);
    } else {
        hipMemsetAsync(out, 0, (size_t)out_size * sizeof(float), stream);
        direct_kernel<<<(V + 1) / 2, 256, 0, stream>>>(x, ht, sp, w, out, V, HW,
                                                       S, CH);
    }
}